// Round 3
// baseline (370.368 us; speedup 1.0000x reference)
//
#include <hip/hip_runtime.h>

#define N_NODES 50000
#define NFEAT 128
#define NEDGE 800000
#define NGRAPH 512
#define NCE 64
#define EPS 1e-5f
#define NBUCK 196            // ceil(50000/256) buckets of 256 nodes
#define EPB 4096             // edges per bucket_scatter block
#define BCAP 6144            // fixed per-bucket capacity (avg 4082, sigma 64 -> +32 sigma)

typedef short s8v __attribute__((ext_vector_type(8)));
typedef float f4v __attribute__((ext_vector_type(4)));
typedef float f2v __attribute__((ext_vector_type(2)));

// ---------- bf16 helpers (manual, bit-exact RNE) ----------
static __device__ __forceinline__ unsigned short f2bf(float f) {
    unsigned int u = __float_as_uint(f);
    unsigned int r = u + 0x7fffu + ((u >> 16) & 1u);
    return (unsigned short)(r >> 16);
}
static __device__ __forceinline__ float bf_lo(unsigned int packed) {
    return __uint_as_float(packed << 16);
}
static __device__ __forceinline__ float bf_hi(unsigned int packed) {
    return __uint_as_float(packed & 0xffff0000u);
}
static __device__ __forceinline__ float bf_us(unsigned short us) {
    return __uint_as_float(((unsigned int)us) << 16);
}
static __device__ __forceinline__ f2v unpk(unsigned int u) {
    f2v r; r.x = bf_lo(u); r.y = bf_hi(u); return r;
}
// LDS XOR swizzle (ushort units): kills the 16-way bank conflict of
// ds_read_b128 on row-major [*][128] bf16 tiles (row stride 256B -> 1 bank).
static __device__ __forceinline__ int swz(int row, int col) {
    return col ^ ((row & 7) << 3);
}
static __device__ __forceinline__ int lbound(const int* __restrict__ a, int n, int key) {
    int lo = 0, hi = n;
    while (lo < hi) { int mid = (lo + hi) >> 1; if (a[mid] < key) lo = mid + 1; else hi = mid; }
    return lo;
}

// ---------- 1. bucket scatter (+ merged weight cast blocks) ----------
__global__ __launch_bounds__(256) void scatter_wcast_kernel(
    const int* __restrict__ ei, int* __restrict__ bucketCursor,
    unsigned int* __restrict__ recbuf, int E,
    const float* __restrict__ W1, const float* __restrict__ W2,
    unsigned short* __restrict__ WT1, unsigned short* __restrict__ WT2)
{
    __shared__ int hist[NBUCK];
    __shared__ int lbase[NBUCK];
    __shared__ int gbase[NBUCK];
    __shared__ int cur[NBUCK];
    __shared__ int scanbuf[256];
    __shared__ unsigned int staging[EPB];
    int tid = threadIdx.x;

    if (blockIdx.x >= NBUCK) {                   // weight-cast blocks
        int b = blockIdx.x - NBUCK;              // 0..127
        const float* W = (b >= 64) ? W2 : W1;
        unsigned short* WT = (b >= 64) ? WT2 : WT1;
        int idx = (b & 63) * 256 + tid;          // 64 blocks x 256 = 16384
        int k = idx >> 7, n2 = idx & 127;
        WT[n2 * 128 + k] = f2bf(W[idx]);
        return;
    }

    if (tid < NBUCK) { hist[tid] = 0; cur[tid] = 0; }
    __syncthreads();

    unsigned int rec[EPB / 256];
    int e0 = blockIdx.x * EPB + tid;
#pragma unroll
    for (int i = 0; i < EPB / 256; ++i) {
        int e = e0 + i * 256;
        if (e < E) {
            unsigned int sv = (unsigned)ei[e];
            unsigned int dv = (unsigned)ei[E + e];
            rec[i] = sv | (dv << 16);
            atomicAdd(&hist[dv >> 8], 1);
        } else {
            rec[i] = 0xffffffffu;
        }
    }
    __syncthreads();
    int v = (tid < NBUCK) ? hist[tid] : 0;
    scanbuf[tid] = v; __syncthreads();
    for (int off = 1; off < 256; off <<= 1) {
        int t = (tid >= off) ? scanbuf[tid - off] : 0;
        __syncthreads();
        scanbuf[tid] += t;
        __syncthreads();
    }
    if (tid < NBUCK) lbase[tid] = scanbuf[tid] - v;
    int total = scanbuf[255];
    if (tid < NBUCK) gbase[tid] = (v > 0) ? atomicAdd(&bucketCursor[tid], v) : 0;
    __syncthreads();
#pragma unroll
    for (int i = 0; i < EPB / 256; ++i) {
        if (rec[i] != 0xffffffffu) {
            int b = rec[i] >> 24;       // dst >> 8
            int loc = atomicAdd(&cur[b], 1);
            staging[lbase[b] + loc] = rec[i];
        }
    }
    __syncthreads();
    for (int s = tid; s < total; s += 256) {
        unsigned int r = staging[s];
        int b = r >> 24;
        int pos = gbase[b] + (s - lbase[b]);
        if (pos < BCAP) recbuf[(size_t)b * BCAP + pos] = r;
    }
}

// ---------- 2. per-bucket CSR finalize (dense buckets) ----------
__global__ __launch_bounds__(256) void bucket_csr_kernel(
    const unsigned int* __restrict__ recbuf, const int* __restrict__ bucketCursor,
    int* __restrict__ rowbeg, unsigned short* __restrict__ deg,
    float* __restrict__ dinv, unsigned short* __restrict__ colidx)
{
    __shared__ int cnt[256];
    __shared__ int cur[256];
    __shared__ int scanbuf[256];
    __shared__ unsigned short stage[BCAP];
    int b = blockIdx.x, tid = threadIdx.x;
    int base = b * BCAP;
    int len = bucketCursor[b]; if (len > BCAP) len = BCAP;
    cnt[tid] = 0;
    __syncthreads();
    for (int s = tid; s < len; s += 256) {
        unsigned int r = recbuf[base + s];
        atomicAdd(&cnt[(r >> 16) & 255], 1);
    }
    __syncthreads();
    int v = cnt[tid];
    scanbuf[tid] = v; __syncthreads();
    for (int off = 1; off < 256; off <<= 1) {
        int t = (tid >= off) ? scanbuf[tid - off] : 0;
        __syncthreads();
        scanbuf[tid] += t;
        __syncthreads();
    }
    int excl = scanbuf[tid] - v;
    int node = b * 256 + tid;
    if (node < N_NODES) {
        rowbeg[node] = base + excl;
        deg[node] = (unsigned short)v;
        dinv[node] = rsqrtf((float)v + 1.0f);
    }
    cur[tid] = excl;
    __syncthreads();
    for (int s = tid; s < len; s += 256) {
        unsigned int r = recbuf[base + s];
        int pos = atomicAdd(&cur[(r >> 16) & 255], 1);
        stage[pos] = (unsigned short)(r & 0xffffu);
    }
    __syncthreads();
    for (int s = tid; s < len; s += 256) colidx[base + s] = stage[s];
}

// ---------- MFMA GEMM: HS[r][c] = bf16( (A @ W)[r][c] * dinv[r] ) ----------
// LDS tiles XOR-swizzled (writer and reader agree): removes 16-way ds_read_b128
// bank conflicts on the 256B-stride rows.
template<bool FP32IN>
__global__ __launch_bounds__(256) void gemm_mfma_kernel(
    const void* __restrict__ Ain, const unsigned short* __restrict__ WTg,
    const float* __restrict__ dinv, unsigned short* __restrict__ HS, int nrows)
{
    __shared__ unsigned short as[128 * 128];   // 32 KB; reused for result staging
    __shared__ unsigned short wt[128 * 128];   // 32 KB
    const int tid = threadIdx.x;
    const int row0 = blockIdx.x * 128;

    {
        const uint4* src = reinterpret_cast<const uint4*>(WTg);
        uint4* dst = reinterpret_cast<uint4*>(wt);
#pragma unroll
        for (int i = 0; i < 8; ++i) {
            int t = tid + i * 256;
            int d = (t & ~15) | ((t & 15) ^ ((t >> 4) & 7));   // swizzled uint4 slot
            dst[d] = src[t];
        }
    }
    if (FP32IN) {
        const float* X = (const float*)Ain;
#pragma unroll
        for (int i = 0; i < 16; ++i) {
            int f = tid + i * 256;
            int r = f >> 5, c4 = f & 31;
            int rr = row0 + r; if (rr >= nrows) rr = nrows - 1;
            float4 v = *reinterpret_cast<const float4*>(&X[rr * 128 + c4 * 4]);
            ushort4 o;
            o.x = f2bf(v.x); o.y = f2bf(v.y); o.z = f2bf(v.z); o.w = f2bf(v.w);
            *reinterpret_cast<ushort4*>(&as[r * 128 + swz(r, c4 * 4)]) = o;
        }
    } else {
        const unsigned short* X = (const unsigned short*)Ain;
#pragma unroll
        for (int i = 0; i < 8; ++i) {
            int f = tid + i * 256;
            int r = f >> 4, c8 = f & 15;
            int rr = row0 + r; if (rr >= nrows) rr = nrows - 1;
            *reinterpret_cast<uint4*>(&as[r * 128 + swz(r, c8 * 8)]) =
                *reinterpret_cast<const uint4*>(&X[rr * 128 + c8 * 8]);
        }
    }
    __syncthreads();

    const int w = tid >> 6;
    const int lane = tid & 63;
    const int quad = lane >> 4;
    const int col0 = lane & 15;

    s8v afr[2][4];
#pragma unroll
    for (int rt = 0; rt < 2; ++rt)
#pragma unroll
        for (int kt = 0; kt < 4; ++kt) {
            int rA = w * 32 + rt * 16 + col0;
            afr[rt][kt] = *reinterpret_cast<const s8v*>(
                &as[rA * 128 + swz(rA, kt * 32 + quad * 8)]);
        }

    f4v acc[2][8];
#pragma unroll
    for (int rt = 0; rt < 2; ++rt)
#pragma unroll
        for (int nt = 0; nt < 8; ++nt)
            acc[rt][nt] = (f4v){0.f, 0.f, 0.f, 0.f};

#pragma unroll
    for (int nt = 0; nt < 8; ++nt) {
        s8v bfr[4];
#pragma unroll
        for (int kt = 0; kt < 4; ++kt) {
            int rB = nt * 16 + col0;
            bfr[kt] = *reinterpret_cast<const s8v*>(
                &wt[rB * 128 + swz(rB, kt * 32 + quad * 8)]);
        }
#pragma unroll
        for (int rt = 0; rt < 2; ++rt)
#pragma unroll
            for (int kt = 0; kt < 4; ++kt)
                acc[rt][nt] = __builtin_amdgcn_mfma_f32_16x16x32_bf16(
                    afr[rt][kt], bfr[kt], acc[rt][nt], 0, 0, 0);
    }

    float dv[2][4];
#pragma unroll
    for (int rt = 0; rt < 2; ++rt)
#pragma unroll
        for (int reg = 0; reg < 4; ++reg) {
            int r = row0 + w * 32 + rt * 16 + quad * 4 + reg;
            dv[rt][reg] = (r < nrows) ? dinv[r] : 0.f;
        }

#pragma unroll
    for (int rt = 0; rt < 2; ++rt)
#pragma unroll
        for (int nt = 0; nt < 8; ++nt)
#pragma unroll
            for (int reg = 0; reg < 4; ++reg) {
                int rl = w * 32 + rt * 16 + quad * 4 + reg;
                as[rl * 128 + swz(rl, nt * 16 + col0)] = f2bf(acc[rt][nt][reg] * dv[rt][reg]);
            }
    __syncthreads();
#pragma unroll
    for (int i = 0; i < 8; ++i) {
        int f = tid + i * 256;
        int r = f >> 4, c8 = f & 15;
        if (row0 + r < nrows)
            *reinterpret_cast<uint4*>(&HS[(size_t)(row0 + r) * 128 + c8 * 8]) =
                *reinterpret_cast<const uint4*>(&as[r * 128 + swz(r, c8 * 8)]);
    }
}

// ---------- shared per-node aggregation body (bit-identical across kernels) ----------
static __device__ __forceinline__ uint2 agg_node(
    const uint2* __restrict__ H2, const int* __restrict__ rowbeg,
    const unsigned short* __restrict__ deg, const unsigned short* __restrict__ colidx,
    const float* __restrict__ dinv, const float* __restrict__ bias,
    int node, int lane)
{
    const int half = lane >> 5;
    const int sub = lane & 31;
    const int beg = rowbeg[node];
    const int cnt = (int)deg[node] + 1;                 // + self
    f2v a01 = {0.f, 0.f}, a23 = {0.f, 0.f};             // bank A
    f2v b01 = {0.f, 0.f}, b23 = {0.f, 0.f};             // bank B
    for (int base = 0; base < cnt; base += 64) {
        int m = cnt - base; if (m > 64) m = 64;
        int p = base + lane;
        int idx = 0;
        if (lane < m) idx = (p == 0) ? node : (int)colidx[beg + p - 1];
        int j = 0;
        for (; j + 16 <= m; j += 16) {                  // 8 pair-loads = 16 rows in flight
            uint2 t[8];
#pragma unroll
            for (int q = 0; q < 8; ++q) {
                int u = __shfl(idx, j + q * 2 + half);
                t[q] = H2[(size_t)u * 32 + sub];
            }
#pragma unroll
            for (int q = 0; q < 8; q += 2) {
                a01 += unpk(t[q].x);     a23 += unpk(t[q].y);
                b01 += unpk(t[q + 1].x); b23 += unpk(t[q + 1].y);
            }
        }
        for (; j + 4 <= m; j += 4) {                    // 2 pair-loads
            int ua = __shfl(idx, j + half);
            int ub = __shfl(idx, j + 2 + half);
            uint2 ta = H2[(size_t)ua * 32 + sub];
            uint2 tb = H2[(size_t)ub * 32 + sub];
            a01 += unpk(ta.x); a23 += unpk(ta.y);
            b01 += unpk(tb.x); b23 += unpk(tb.y);
        }
        if (j + 2 <= m) {                               // 1 pair-load
            int u = __shfl(idx, j + half);
            uint2 t = H2[(size_t)u * 32 + sub];
            a01 += unpk(t.x); a23 += unpk(t.y);
            j += 2;
        }
        if (j < m) {                                    // odd singleton: half 0 only
            int u = __shfl(idx, j);
            uint2 t; t.x = 0u; t.y = 0u;
            if (half == 0) t = H2[(size_t)u * 32 + sub];
            a01 += unpk(t.x); a23 += unpk(t.y);
        }
    }
    a01 += b01; a23 += b23;
    float s0 = a01.x + __shfl_xor(a01.x, 32);
    float s1 = a01.y + __shfl_xor(a01.y, 32);
    float s2 = a23.x + __shfl_xor(a23.x, 32);
    float s3 = a23.y + __shfl_xor(a23.y, 32);
    float sc = dinv[node];
    float4 bv = *reinterpret_cast<const float4*>(&bias[sub * 4]);
    float o0 = fmaxf(fmaf(s0, sc, bv.x), 0.f);
    float o1 = fmaxf(fmaf(s1, sc, bv.y), 0.f);
    float o2 = fmaxf(fmaf(s2, sc, bv.z), 0.f);
    float o3 = fmaxf(fmaf(s3, sc, bv.w), 0.f);
    uint2 o;
    o.x = (unsigned int)f2bf(o0) | ((unsigned int)f2bf(o1) << 16);
    o.y = (unsigned int)f2bf(o2) | ((unsigned int)f2bf(o3) << 16);
    return o;
}

// ---------- FUSED: aggregate(conv1 epilogue) -> LDS -> MFMA @ W2 -> *dinv -> HS2 ----------
__global__ __launch_bounds__(1024, 8) void fused_agg_gemm_kernel(
    const uint2* __restrict__ H2, const int* __restrict__ rowbeg,
    const unsigned short* __restrict__ deg, const unsigned short* __restrict__ colidx,
    const float* __restrict__ dinv, const float* __restrict__ bias,
    const unsigned short* __restrict__ WTg, unsigned short* __restrict__ HS2, int n)
{
    __shared__ unsigned short as[128 * 128];   // 32 KB: gathered h1 tile (swizzled), then result
    __shared__ unsigned short wt[128 * 128];   // 32 KB: W2^T (swizzled)
    __shared__ int nodeCur;
    const int tid = threadIdx.x;
    const int row0 = blockIdx.x * 128;

    if (tid == 0) nodeCur = 0;
    {
        const uint4* src = reinterpret_cast<const uint4*>(WTg);
        uint4* dst = reinterpret_cast<uint4*>(wt);
        int t0 = tid, t1 = tid + 1024;
        dst[(t0 & ~15) | ((t0 & 15) ^ ((t0 >> 4) & 7))] = src[t0];
        dst[(t1 & ~15) | ((t1 & 15) ^ ((t1 >> 4) & 7))] = src[t1];
    }
    __syncthreads();                           // nodeCur visible

    const int w16 = tid >> 6;
    const int lane = tid & 63;

    // ---- phase A: dynamic-cursor aggregation into (swizzled) LDS ----
    uint2* asu2 = reinterpret_cast<uint2*>(as);
    for (;;) {
        int rr = 0;
        if (lane == 0) rr = atomicAdd(&nodeCur, 1);
        rr = __shfl(rr, 0);
        if (rr >= 128) break;
        int node = row0 + rr;
        if (node < n) {
            uint2 o = agg_node(H2, rowbeg, deg, colidx, dinv, bias, node, lane);
            if ((lane >> 5) == 0) {
                int sub = lane & 31;
                asu2[rr * 32 + (sub ^ ((rr & 7) << 1))] = o;   // = ushort swz(rr, sub*4)/4
            }
        }
    }
    __syncthreads();

    // ---- phase B: as(128x128 bf16 h1-tile) @ wt -> *dinv -> HS2 ----
    const int quad = lane >> 4;
    const int col0 = lane & 15;
    const int wr  = w16 >> 1;        // rowtile 0..7
    const int nt0 = (w16 & 1) * 4;   // coltile base (0 or 4)

    s8v afr[4];
#pragma unroll
    for (int kt = 0; kt < 4; ++kt) {
        int rA = wr * 16 + col0;
        afr[kt] = *reinterpret_cast<const s8v*>(
            &as[rA * 128 + swz(rA, kt * 32 + quad * 8)]);
    }

    f4v acc[4];
#pragma unroll
    for (int nt = 0; nt < 4; ++nt) acc[nt] = (f4v){0.f, 0.f, 0.f, 0.f};

#pragma unroll
    for (int nt = 0; nt < 4; ++nt) {
        s8v bfr[4];
#pragma unroll
        for (int kt = 0; kt < 4; ++kt) {
            int rB = (nt0 + nt) * 16 + col0;
            bfr[kt] = *reinterpret_cast<const s8v*>(
                &wt[rB * 128 + swz(rB, kt * 32 + quad * 8)]);
        }
#pragma unroll
        for (int kt = 0; kt < 4; ++kt)
            acc[nt] = __builtin_amdgcn_mfma_f32_16x16x32_bf16(
                afr[kt], bfr[kt], acc[nt], 0, 0, 0);
    }

    float dv[4];
#pragma unroll
    for (int reg = 0; reg < 4; ++reg) {
        int r = row0 + wr * 16 + quad * 4 + reg;
        dv[reg] = (r < n) ? dinv[r] : 0.f;
    }
    __syncthreads();                 // all afr reads done before as overwrite
#pragma unroll
    for (int nt = 0; nt < 4; ++nt)
#pragma unroll
        for (int reg = 0; reg < 4; ++reg) {
            int rl = wr * 16 + quad * 4 + reg;
            as[rl * 128 + swz(rl, (nt0 + nt) * 16 + col0)] = f2bf(acc[nt][reg] * dv[reg]);
        }
    __syncthreads();
#pragma unroll
    for (int i = 0; i < 2; ++i) {
        int f = tid + i * 1024;
        int r = f >> 4, c8 = f & 15;
        if (row0 + r < n)
            *reinterpret_cast<uint4*>(&HS2[(size_t)(row0 + r) * 128 + c8 * 8]) =
                *reinterpret_cast<const uint4*>(&as[r * 128 + swz(r, c8 * 8)]);
    }
}

// ---------- per-graph MLP (identical math to old tail_kernel), runs inside agg_pool ----------
static __device__ void mlp_graph(int gi, int tid,
    float* __restrict__ pooled, const int* __restrict__ cell, const float* __restrict__ emb,
    const float* __restrict__ Wc, const float* __restrict__ bc,
    const float* __restrict__ lncw, const float* __restrict__ lncb,
    const float* __restrict__ Wf1, const float* __restrict__ bf1,
    const float* __restrict__ ln1w, const float* __restrict__ ln1b,
    const float* __restrict__ Wf2, const float* __restrict__ bf2,
    float* __restrict__ out,
    float* comb, float (*part)[132], float* red, float* vec)
{
    const int cg = tid & 31;
    const int ks = tid >> 5;

    if (tid < 128) comb[tid] = atomicAdd(&pooled[gi * 128 + tid], 0.0f);  // coherent read
    else if (tid < 192) comb[tid] = emb[cell[gi] * 64 + (tid - 128)];
    __syncthreads();

    // ---- layer A: comb @ Wc ----
    if (tid < 256) {
        float c[24];
#pragma unroll
        for (int i = 0; i < 6; ++i) {
            float4 t = *reinterpret_cast<const float4*>(&comb[ks * 24 + i * 4]);
            c[i * 4 + 0] = t.x; c[i * 4 + 1] = t.y; c[i * 4 + 2] = t.z; c[i * 4 + 3] = t.w;
        }
        float a0 = 0.f, a1 = 0.f, a2 = 0.f, a3 = 0.f;
#pragma unroll
        for (int i = 0; i < 24; ++i) {
            const float4 w = *reinterpret_cast<const float4*>(&Wc[(ks * 24 + i) * 128 + cg * 4]);
            a0 = fmaf(c[i], w.x, a0);
            a1 = fmaf(c[i], w.y, a1);
            a2 = fmaf(c[i], w.z, a2);
            a3 = fmaf(c[i], w.w, a3);
        }
        float4 o; o.x = a0; o.y = a1; o.z = a2; o.w = a3;
        *reinterpret_cast<float4*>(&part[ks][cg * 4]) = o;
    }
    __syncthreads();
    {
        float y = 0.f;
        if (tid < 128) {
            y = bc[tid];
#pragma unroll
            for (int s = 0; s < 8; ++s) y += part[s][tid];
        }
        float s1 = (tid < 128) ? y : 0.f;
        float s2 = (tid < 128) ? y * y : 0.f;
        if (tid < 128) {
#pragma unroll
            for (int off = 32; off > 0; off >>= 1) {
                s1 += __shfl_down(s1, off);
                s2 += __shfl_down(s2, off);
            }
            if ((tid & 63) == 0) { red[(tid >> 6) * 2] = s1; red[(tid >> 6) * 2 + 1] = s2; }
        }
        __syncthreads();
        float mu = (red[0] + red[2]) * (1.f / 128.f);
        float ms = (red[1] + red[3]) * (1.f / 128.f);
        float var = ms - mu * mu;
        if (tid < 128) {
            float yv = (y - mu) * rsqrtf(var + EPS) * lncw[tid] + lncb[tid];
            vec[tid] = fmaxf(yv, 0.f);
        }
    }
    __syncthreads();

    // ---- layer B: vec @ Wf1, relu, LN ----
    if (tid < 256) {
        float c[16];
#pragma unroll
        for (int i = 0; i < 4; ++i) {
            float4 t = *reinterpret_cast<const float4*>(&vec[ks * 16 + i * 4]);
            c[i * 4 + 0] = t.x; c[i * 4 + 1] = t.y; c[i * 4 + 2] = t.z; c[i * 4 + 3] = t.w;
        }
        float a0 = 0.f, a1 = 0.f, a2 = 0.f, a3 = 0.f;
#pragma unroll
        for (int i = 0; i < 16; ++i) {
            const float4 w = *reinterpret_cast<const float4*>(&Wf1[(ks * 16 + i) * 128 + cg * 4]);
            a0 = fmaf(c[i], w.x, a0);
            a1 = fmaf(c[i], w.y, a1);
            a2 = fmaf(c[i], w.z, a2);
            a3 = fmaf(c[i], w.w, a3);
        }
        float4 o; o.x = a0; o.y = a1; o.z = a2; o.w = a3;
        *reinterpret_cast<float4*>(&part[ks][cg * 4]) = o;
    }
    __syncthreads();
    {
        float y = 0.f;
        if (tid < 128) {
            y = bf1[tid];
#pragma unroll
            for (int s = 0; s < 8; ++s) y += part[s][tid];
            y = fmaxf(y, 0.f);                 // relu BEFORE LN
        }
        float s1 = (tid < 128) ? y : 0.f;
        float s2 = (tid < 128) ? y * y : 0.f;
        if (tid < 128) {
#pragma unroll
            for (int off = 32; off > 0; off >>= 1) {
                s1 += __shfl_down(s1, off);
                s2 += __shfl_down(s2, off);
            }
            if ((tid & 63) == 0) { red[(tid >> 6) * 2] = s1; red[(tid >> 6) * 2 + 1] = s2; }
        }
        __syncthreads();
        float mu = (red[0] + red[2]) * (1.f / 128.f);
        float ms = (red[1] + red[3]) * (1.f / 128.f);
        float var = ms - mu * mu;
        if (tid < 128)
            vec[tid] = (y - mu) * rsqrtf(var + EPS) * ln1w[tid] + ln1b[tid];   // no relu
    }
    __syncthreads();

    // ---- layer C: vec @ Wf2 ----
    if (tid < 256) {
        float c[16];
#pragma unroll
        for (int i = 0; i < 4; ++i) {
            float4 t = *reinterpret_cast<const float4*>(&vec[ks * 16 + i * 4]);
            c[i * 4 + 0] = t.x; c[i * 4 + 1] = t.y; c[i * 4 + 2] = t.z; c[i * 4 + 3] = t.w;
        }
        float a0 = 0.f, a1 = 0.f, a2 = 0.f, a3 = 0.f;
#pragma unroll
        for (int i = 0; i < 16; ++i) {
            const float4 w = *reinterpret_cast<const float4*>(&Wf2[(ks * 16 + i) * 128 + cg * 4]);
            a0 = fmaf(c[i], w.x, a0);
            a1 = fmaf(c[i], w.y, a1);
            a2 = fmaf(c[i], w.z, a2);
            a3 = fmaf(c[i], w.w, a3);
        }
        float4 o; o.x = a0; o.y = a1; o.z = a2; o.w = a3;
        *reinterpret_cast<float4*>(&part[ks][cg * 4]) = o;
    }
    __syncthreads();
    if (tid < 128) {
        float y = bf2[tid];
#pragma unroll
        for (int s = 0; s < 8; ++s) y += part[s][tid];
        out[gi * 128 + tid] = y;
    }
    __syncthreads();
}

// ---------- FUSED: conv2 aggregate -> segment-pool -> atomicAdd -> last-block tail MLP ----------
__global__ __launch_bounds__(1024, 8) void agg_pool_tail_kernel(
    const uint2* __restrict__ H2, const int* __restrict__ rowbeg,
    const unsigned short* __restrict__ deg, const unsigned short* __restrict__ colidx,
    const float* __restrict__ dinv, const float* __restrict__ bias,
    const int* __restrict__ batch, float* __restrict__ pooled, int* __restrict__ blkCnt,
    const int* __restrict__ cell, const float* __restrict__ emb,
    const float* __restrict__ Wc, const float* __restrict__ bc,
    const float* __restrict__ lncw, const float* __restrict__ lncb,
    const float* __restrict__ Wf1, const float* __restrict__ bf1,
    const float* __restrict__ ln1w, const float* __restrict__ ln1b,
    const float* __restrict__ Wf2, const float* __restrict__ bf2,
    float* __restrict__ out, int n)
{
    __shared__ unsigned short as[128 * 128];   // 32 KB: bf16 conv2 rows (linear layout)
    __shared__ int bsh[128];
    __shared__ float psum[8][132];
    __shared__ int nodeCur;
    __shared__ __align__(16) float comb[192];
    __shared__ float red[4];
    __shared__ __align__(16) float vec[128];
    __shared__ int claim[130];
    __shared__ int nclaim;
    const int tid = threadIdx.x;
    const int row0 = blockIdx.x * 128;
    if (tid == 0) { nodeCur = 0; nclaim = 0; }
    if (tid < 128) bsh[tid] = (row0 + tid < n) ? batch[row0 + tid] : -1;
    __syncthreads();

    const int lane = tid & 63;
    uint2* asu2 = reinterpret_cast<uint2*>(as);
    for (;;) {
        int rr = 0;
        if (lane == 0) rr = atomicAdd(&nodeCur, 1);
        rr = __shfl(rr, 0);
        if (rr >= 128) break;
        int node = row0 + rr;
        if (node < n) {
            uint2 o = agg_node(H2, rowbeg, deg, colidx, dinv, bias, node, lane);
            if ((lane >> 5) == 0) asu2[rr * 32 + (lane & 31)] = o;
        }
    }
    __syncthreads();

    const int g0 = bsh[0];
    int last = row0 + 127; if (last > n - 1) last = n - 1;
    const int g1 = batch[last];
    const int s = tid >> 7;          // stripe 0..7
    const int f = tid & 127;
    for (int g = g0; g <= g1; ++g) {
        float acc = 0.f;
        for (int r = s; r < 128; r += 8)
            if (bsh[r] == g) acc += bf_us(as[r * 128 + f]);
        psum[s][f] = acc;
        __syncthreads();
        if (tid < 128) {
            float tot = 0.f;
#pragma unroll
            for (int q = 0; q < 8; ++q) tot += psum[q][f];
            atomicAdd(&pooled[g * 128 + f], tot);
        }
        __syncthreads();
    }

    // ---- claim completed graphs (last contributing block runs the MLP) ----
    __threadfence();                 // pooled adds visible before blkCnt bump
    __syncthreads();
    if (tid == 0) {
        int nc = 0;
        for (int g = g0; g <= g1; ++g) {
            int fb = (g == g0) ? (lbound(batch, n, g) >> 7) : blockIdx.x;
            int lb2 = (g == g1) ? ((lbound(batch, n, g + 1) - 1) >> 7) : blockIdx.x;
            int expected = lb2 - fb + 1;
            int old = atomicAdd(&blkCnt[g], 1);
            if (old == expected - 1) claim[nc++] = g;
        }
        nclaim = nc;
    }
    __syncthreads();
    const int nc = nclaim;
    for (int ci = 0; ci < nc; ++ci)
        mlp_graph(claim[ci], tid, pooled, cell, emb, Wc, bc, lncw, lncb,
                  Wf1, bf1, ln1w, ln1b, Wf2, bf2, out, comb, psum, red, vec);

    // ---- empty-graph sweep (statistically ~never, but must not drop rows) ----
    if (blockIdx.x == gridDim.x - 1) {
        if (tid == 0) nclaim = 0;
        __syncthreads();
        if (tid < NGRAPH) {
            int s0 = lbound(batch, n, tid);
            if (s0 >= n || batch[s0] != tid) {
                int k = atomicAdd(&nclaim, 1);
                if (k < 130) claim[k] = tid;
            }
        }
        __syncthreads();
        int ne = nclaim; if (ne > 130) ne = 130;
        for (int i = 0; i < ne; ++i)
            mlp_graph(claim[i], tid, pooled, cell, emb, Wc, bc, lncw, lncb,
                      Wf1, bf1, ln1w, ln1b, Wf2, bf2, out, comb, psum, red, vec);
    }
}

// ---------- host launch ----------
extern "C" void kernel_launch(void* const* d_in, const int* in_sizes, int n_in,
                              void* d_out, int out_size, void* d_ws, size_t ws_size,
                              hipStream_t stream) {
    const float* x    = (const float*)d_in[0];
    const int*   ei   = (const int*)d_in[1];
    const int*   batch= (const int*)d_in[2];
    const int*   cell = (const int*)d_in[3];
    const float* W1   = (const float*)d_in[4];
    const float* b1   = (const float*)d_in[5];
    const float* W2   = (const float*)d_in[6];
    const float* b2   = (const float*)d_in[7];
    const float* emb  = (const float*)d_in[8];
    const float* Wc   = (const float*)d_in[9];
    const float* bc   = (const float*)d_in[10];
    const float* lncw = (const float*)d_in[11];
    const float* lncb = (const float*)d_in[12];
    const float* Wf1  = (const float*)d_in[13];
    const float* bf1  = (const float*)d_in[14];
    const float* ln1w = (const float*)d_in[15];
    const float* ln1b = (const float*)d_in[16];
    const float* Wf2  = (const float*)d_in[17];
    const float* bf2  = (const float*)d_in[18];
    float* out = (float*)d_out;

    char* ws = (char*)d_ws;
    size_t off = 0;
    auto alloc = [&](size_t bytes) { char* p = ws + off; off = (off + bytes + 255) & ~size_t(255); return p; };
    // bucketCursor + blkCnt + pooled adjacent -> single memset clears all
    int*            bucketCursor= (int*)  alloc(4096);                    // [0..195] cursor, [256..767] blkCnt
    float*          pooled      = (float*)alloc((size_t)NGRAPH * 128 * 4);// 256 KB
    int*            blkCnt      = bucketCursor + 256;
    float*          dinv        = (float*)alloc(N_NODES * 4);
    int*            rowbeg      = (int*)  alloc(N_NODES * 4);
    unsigned short* deg         = (unsigned short*)alloc(N_NODES * 2);
    unsigned short* colidx      = (unsigned short*)alloc((size_t)NBUCK * BCAP * 2);
    unsigned int*   recbuf      = (unsigned int*)alloc((size_t)NBUCK * BCAP * 4);
    unsigned short* wt1         = (unsigned short*)alloc(128 * 128 * 2);
    unsigned short* wt2         = (unsigned short*)alloc(128 * 128 * 2);
    unsigned short* hs          = (unsigned short*)alloc((size_t)N_NODES * 128 * 2);
    unsigned short* hs2         = (unsigned short*)alloc((size_t)N_NODES * 128 * 2);

    const int nbEdge = (NEDGE + EPB - 1) / EPB;        // 196
    const int nbGemm = (N_NODES + 127) / 128;          // 391

    // zero cursor + blkCnt + pooled (stream-ordered memset node; capture-safe)
    hipMemsetAsync(bucketCursor, 0, 4096 + (size_t)NGRAPH * 128 * 4, stream);

    // scatter + weight cast (merged)
    scatter_wcast_kernel<<<nbEdge + 128, 256, 0, stream>>>(ei, bucketCursor, recbuf, NEDGE,
                                                           W1, W2, wt1, wt2);
    bucket_csr_kernel<<<NBUCK, 256, 0, stream>>>(recbuf, bucketCursor, rowbeg, deg, dinv, colidx);

    // conv1 GEMM: hs = (X @ W1) * dinv
    gemm_mfma_kernel<true><<<nbGemm, 256, 0, stream>>>(x, wt1, dinv, hs, N_NODES);

    // FUSED: agg(conv1 epilogue: +b1, relu) -> LDS tile -> @W2 -> *dinv -> hs2
    fused_agg_gemm_kernel<<<nbGemm, 1024, 0, stream>>>(
        (const uint2*)hs, rowbeg, deg, colidx, dinv, b1, wt2, hs2, N_NODES);

    // FUSED: conv2 aggregate + segment pooling + last-block tail MLP
    agg_pool_tail_kernel<<<nbGemm, 1024, 0, stream>>>(
        (const uint2*)hs2, rowbeg, deg, colidx, dinv, b2, batch, pooled, blkCnt,
        cell, emb, Wc, bc, lncw, lncb, Wf1, bf1, ln1w, ln1b, Wf2, bf2, out, N_NODES);
}

// Round 4
// 212.638 us; speedup vs baseline: 1.7418x; 1.7418x over previous
//
#include <hip/hip_runtime.h>

#define N_NODES 50000
#define NFEAT 128
#define NEDGE 800000
#define NGRAPH 512
#define NCE 64
#define EPS 1e-5f
#define NBUCK 196            // ceil(50000/256) buckets of 256 nodes
#define EPB 4096             // edges per bucket_scatter block
#define BCAP 6144            // fixed per-bucket capacity (avg 4082, sigma 64 -> +32 sigma)

typedef short s8v __attribute__((ext_vector_type(8)));
typedef float f4v __attribute__((ext_vector_type(4)));
typedef float f2v __attribute__((ext_vector_type(2)));

// ---------- bf16 helpers (manual, bit-exact RNE) ----------
static __device__ __forceinline__ unsigned short f2bf(float f) {
    unsigned int u = __float_as_uint(f);
    unsigned int r = u + 0x7fffu + ((u >> 16) & 1u);
    return (unsigned short)(r >> 16);
}
static __device__ __forceinline__ float bf_lo(unsigned int packed) {
    return __uint_as_float(packed << 16);
}
static __device__ __forceinline__ float bf_hi(unsigned int packed) {
    return __uint_as_float(packed & 0xffff0000u);
}
static __device__ __forceinline__ float bf_us(unsigned short us) {
    return __uint_as_float(((unsigned int)us) << 16);
}
static __device__ __forceinline__ f2v unpk(unsigned int u) {
    f2v r; r.x = bf_lo(u); r.y = bf_hi(u); return r;
}
// LDS XOR swizzle (ushort units): kills the 16-way bank conflict of
// ds_read_b128 on row-major [*][128] bf16 tiles (row stride 256B -> 1 bank).
static __device__ __forceinline__ int swz(int row, int col) {
    return col ^ ((row & 7) << 3);
}

// ---------- 1. bucket scatter (+ merged weight cast blocks) ----------
__global__ __launch_bounds__(256) void scatter_wcast_kernel(
    const int* __restrict__ ei, int* __restrict__ bucketCursor,
    unsigned int* __restrict__ recbuf, int E,
    const float* __restrict__ W1, const float* __restrict__ W2,
    unsigned short* __restrict__ WT1, unsigned short* __restrict__ WT2)
{
    __shared__ int hist[NBUCK];
    __shared__ int lbase[NBUCK];
    __shared__ int gbase[NBUCK];
    __shared__ int cur[NBUCK];
    __shared__ int scanbuf[256];
    __shared__ unsigned int staging[EPB];
    int tid = threadIdx.x;

    if (blockIdx.x >= NBUCK) {                   // weight-cast blocks
        int b = blockIdx.x - NBUCK;              // 0..127
        const float* W = (b >= 64) ? W2 : W1;
        unsigned short* WT = (b >= 64) ? WT2 : WT1;
        int idx = (b & 63) * 256 + tid;          // 64 blocks x 256 = 16384
        int k = idx >> 7, n2 = idx & 127;
        WT[n2 * 128 + k] = f2bf(W[idx]);
        return;
    }

    if (tid < NBUCK) { hist[tid] = 0; cur[tid] = 0; }
    __syncthreads();

    unsigned int rec[EPB / 256];
    int e0 = blockIdx.x * EPB + tid;
#pragma unroll
    for (int i = 0; i < EPB / 256; ++i) {
        int e = e0 + i * 256;
        if (e < E) {
            unsigned int sv = (unsigned)ei[e];
            unsigned int dv = (unsigned)ei[E + e];
            rec[i] = sv | (dv << 16);
            atomicAdd(&hist[dv >> 8], 1);
        } else {
            rec[i] = 0xffffffffu;
        }
    }
    __syncthreads();
    int v = (tid < NBUCK) ? hist[tid] : 0;
    scanbuf[tid] = v; __syncthreads();
    for (int off = 1; off < 256; off <<= 1) {
        int t = (tid >= off) ? scanbuf[tid - off] : 0;
        __syncthreads();
        scanbuf[tid] += t;
        __syncthreads();
    }
    if (tid < NBUCK) lbase[tid] = scanbuf[tid] - v;
    int total = scanbuf[255];
    if (tid < NBUCK) gbase[tid] = (v > 0) ? atomicAdd(&bucketCursor[tid], v) : 0;
    __syncthreads();
#pragma unroll
    for (int i = 0; i < EPB / 256; ++i) {
        if (rec[i] != 0xffffffffu) {
            int b = rec[i] >> 24;       // dst >> 8
            int loc = atomicAdd(&cur[b], 1);
            staging[lbase[b] + loc] = rec[i];
        }
    }
    __syncthreads();
    for (int s = tid; s < total; s += 256) {
        unsigned int r = staging[s];
        int b = r >> 24;
        int pos = gbase[b] + (s - lbase[b]);
        if (pos < BCAP) recbuf[(size_t)b * BCAP + pos] = r;
    }
}

// ---------- 2. per-bucket CSR finalize (dense buckets) ----------
__global__ __launch_bounds__(256) void bucket_csr_kernel(
    const unsigned int* __restrict__ recbuf, const int* __restrict__ bucketCursor,
    int* __restrict__ rowbeg, unsigned short* __restrict__ deg,
    float* __restrict__ dinv, unsigned short* __restrict__ colidx)
{
    __shared__ int cnt[256];
    __shared__ int cur[256];
    __shared__ int scanbuf[256];
    __shared__ unsigned short stage[BCAP];
    int b = blockIdx.x, tid = threadIdx.x;
    int base = b * BCAP;
    int len = bucketCursor[b]; if (len > BCAP) len = BCAP;
    cnt[tid] = 0;
    __syncthreads();
    for (int s = tid; s < len; s += 256) {
        unsigned int r = recbuf[base + s];
        atomicAdd(&cnt[(r >> 16) & 255], 1);
    }
    __syncthreads();
    int v = cnt[tid];
    scanbuf[tid] = v; __syncthreads();
    for (int off = 1; off < 256; off <<= 1) {
        int t = (tid >= off) ? scanbuf[tid - off] : 0;
        __syncthreads();
        scanbuf[tid] += t;
        __syncthreads();
    }
    int excl = scanbuf[tid] - v;
    int node = b * 256 + tid;
    if (node < N_NODES) {
        rowbeg[node] = base + excl;
        deg[node] = (unsigned short)v;
        dinv[node] = rsqrtf((float)v + 1.0f);
    }
    cur[tid] = excl;
    __syncthreads();
    for (int s = tid; s < len; s += 256) {
        unsigned int r = recbuf[base + s];
        int pos = atomicAdd(&cur[(r >> 16) & 255], 1);
        stage[pos] = (unsigned short)(r & 0xffffu);
    }
    __syncthreads();
    for (int s = tid; s < len; s += 256) colidx[base + s] = stage[s];
}

// ---------- MFMA GEMM: HS[r][c] = bf16( (A @ W)[r][c] * dinv[r] ) ----------
// LDS tiles XOR-swizzled (writer and reader agree): removes 16-way ds_read_b128
// bank conflicts on the 256B-stride rows.
template<bool FP32IN>
__global__ __launch_bounds__(256) void gemm_mfma_kernel(
    const void* __restrict__ Ain, const unsigned short* __restrict__ WTg,
    const float* __restrict__ dinv, unsigned short* __restrict__ HS, int nrows)
{
    __shared__ unsigned short as[128 * 128];   // 32 KB; reused for result staging
    __shared__ unsigned short wt[128 * 128];   // 32 KB
    const int tid = threadIdx.x;
    const int row0 = blockIdx.x * 128;

    {
        const uint4* src = reinterpret_cast<const uint4*>(WTg);
        uint4* dst = reinterpret_cast<uint4*>(wt);
#pragma unroll
        for (int i = 0; i < 8; ++i) {
            int t = tid + i * 256;
            int d = (t & ~15) | ((t & 15) ^ ((t >> 4) & 7));   // swizzled uint4 slot
            dst[d] = src[t];
        }
    }
    if (FP32IN) {
        const float* X = (const float*)Ain;
#pragma unroll
        for (int i = 0; i < 16; ++i) {
            int f = tid + i * 256;
            int r = f >> 5, c4 = f & 31;
            int rr = row0 + r; if (rr >= nrows) rr = nrows - 1;
            float4 v = *reinterpret_cast<const float4*>(&X[rr * 128 + c4 * 4]);
            ushort4 o;
            o.x = f2bf(v.x); o.y = f2bf(v.y); o.z = f2bf(v.z); o.w = f2bf(v.w);
            *reinterpret_cast<ushort4*>(&as[r * 128 + swz(r, c4 * 4)]) = o;
        }
    } else {
        const unsigned short* X = (const unsigned short*)Ain;
#pragma unroll
        for (int i = 0; i < 8; ++i) {
            int f = tid + i * 256;
            int r = f >> 4, c8 = f & 15;
            int rr = row0 + r; if (rr >= nrows) rr = nrows - 1;
            *reinterpret_cast<uint4*>(&as[r * 128 + swz(r, c8 * 8)]) =
                *reinterpret_cast<const uint4*>(&X[rr * 128 + c8 * 8]);
        }
    }
    __syncthreads();

    const int w = tid >> 6;
    const int lane = tid & 63;
    const int quad = lane >> 4;
    const int col0 = lane & 15;

    s8v afr[2][4];
#pragma unroll
    for (int rt = 0; rt < 2; ++rt)
#pragma unroll
        for (int kt = 0; kt < 4; ++kt) {
            int rA = w * 32 + rt * 16 + col0;
            afr[rt][kt] = *reinterpret_cast<const s8v*>(
                &as[rA * 128 + swz(rA, kt * 32 + quad * 8)]);
        }

    f4v acc[2][8];
#pragma unroll
    for (int rt = 0; rt < 2; ++rt)
#pragma unroll
        for (int nt = 0; nt < 8; ++nt)
            acc[rt][nt] = (f4v){0.f, 0.f, 0.f, 0.f};

#pragma unroll
    for (int nt = 0; nt < 8; ++nt) {
        s8v bfr[4];
#pragma unroll
        for (int kt = 0; kt < 4; ++kt) {
            int rB = nt * 16 + col0;
            bfr[kt] = *reinterpret_cast<const s8v*>(
                &wt[rB * 128 + swz(rB, kt * 32 + quad * 8)]);
        }
#pragma unroll
        for (int rt = 0; rt < 2; ++rt)
#pragma unroll
            for (int kt = 0; kt < 4; ++kt)
                acc[rt][nt] = __builtin_amdgcn_mfma_f32_16x16x32_bf16(
                    afr[rt][kt], bfr[kt], acc[rt][nt], 0, 0, 0);
    }

    float dv[2][4];
#pragma unroll
    for (int rt = 0; rt < 2; ++rt)
#pragma unroll
        for (int reg = 0; reg < 4; ++reg) {
            int r = row0 + w * 32 + rt * 16 + quad * 4 + reg;
            dv[rt][reg] = (r < nrows) ? dinv[r] : 0.f;
        }

#pragma unroll
    for (int rt = 0; rt < 2; ++rt)
#pragma unroll
        for (int nt = 0; nt < 8; ++nt)
#pragma unroll
            for (int reg = 0; reg < 4; ++reg) {
                int rl = w * 32 + rt * 16 + quad * 4 + reg;
                as[rl * 128 + swz(rl, nt * 16 + col0)] = f2bf(acc[rt][nt][reg] * dv[rt][reg]);
            }
    __syncthreads();
#pragma unroll
    for (int i = 0; i < 8; ++i) {
        int f = tid + i * 256;
        int r = f >> 4, c8 = f & 15;
        if (row0 + r < nrows)
            *reinterpret_cast<uint4*>(&HS[(size_t)(row0 + r) * 128 + c8 * 8]) =
                *reinterpret_cast<const uint4*>(&as[r * 128 + swz(r, c8 * 8)]);
    }
}

// ---------- shared per-node aggregation body (bit-identical across kernels) ----------
static __device__ __forceinline__ uint2 agg_node(
    const uint2* __restrict__ H2, const int* __restrict__ rowbeg,
    const unsigned short* __restrict__ deg, const unsigned short* __restrict__ colidx,
    const float* __restrict__ dinv, const float* __restrict__ bias,
    int node, int lane)
{
    const int half = lane >> 5;
    const int sub = lane & 31;
    const int beg = rowbeg[node];
    const int cnt = (int)deg[node] + 1;                 // + self
    f2v a01 = {0.f, 0.f}, a23 = {0.f, 0.f};             // bank A
    f2v b01 = {0.f, 0.f}, b23 = {0.f, 0.f};             // bank B
    for (int base = 0; base < cnt; base += 64) {
        int m = cnt - base; if (m > 64) m = 64;
        int p = base + lane;
        int idx = 0;
        if (lane < m) idx = (p == 0) ? node : (int)colidx[beg + p - 1];
        int j = 0;
        for (; j + 16 <= m; j += 16) {                  // 8 pair-loads = 16 rows in flight
            uint2 t[8];
#pragma unroll
            for (int q = 0; q < 8; ++q) {
                int u = __shfl(idx, j + q * 2 + half);
                t[q] = H2[(size_t)u * 32 + sub];
            }
#pragma unroll
            for (int q = 0; q < 8; q += 2) {
                a01 += unpk(t[q].x);     a23 += unpk(t[q].y);
                b01 += unpk(t[q + 1].x); b23 += unpk(t[q + 1].y);
            }
        }
        for (; j + 4 <= m; j += 4) {                    // 2 pair-loads
            int ua = __shfl(idx, j + half);
            int ub = __shfl(idx, j + 2 + half);
            uint2 ta = H2[(size_t)ua * 32 + sub];
            uint2 tb = H2[(size_t)ub * 32 + sub];
            a01 += unpk(ta.x); a23 += unpk(ta.y);
            b01 += unpk(tb.x); b23 += unpk(tb.y);
        }
        if (j + 2 <= m) {                               // 1 pair-load
            int u = __shfl(idx, j + half);
            uint2 t = H2[(size_t)u * 32 + sub];
            a01 += unpk(t.x); a23 += unpk(t.y);
            j += 2;
        }
        if (j < m) {                                    // odd singleton: half 0 only
            int u = __shfl(idx, j);
            uint2 t; t.x = 0u; t.y = 0u;
            if (half == 0) t = H2[(size_t)u * 32 + sub];
            a01 += unpk(t.x); a23 += unpk(t.y);
        }
    }
    a01 += b01; a23 += b23;
    float s0 = a01.x + __shfl_xor(a01.x, 32);
    float s1 = a01.y + __shfl_xor(a01.y, 32);
    float s2 = a23.x + __shfl_xor(a23.x, 32);
    float s3 = a23.y + __shfl_xor(a23.y, 32);
    float sc = dinv[node];
    float4 bv = *reinterpret_cast<const float4*>(&bias[sub * 4]);
    float o0 = fmaxf(fmaf(s0, sc, bv.x), 0.f);
    float o1 = fmaxf(fmaf(s1, sc, bv.y), 0.f);
    float o2 = fmaxf(fmaf(s2, sc, bv.z), 0.f);
    float o3 = fmaxf(fmaf(s3, sc, bv.w), 0.f);
    uint2 o;
    o.x = (unsigned int)f2bf(o0) | ((unsigned int)f2bf(o1) << 16);
    o.y = (unsigned int)f2bf(o2) | ((unsigned int)f2bf(o3) << 16);
    return o;
}

// ---------- FUSED: aggregate(conv1 epilogue) -> LDS -> MFMA @ W2 -> *dinv -> HS2 ----------
__global__ __launch_bounds__(1024, 8) void fused_agg_gemm_kernel(
    const uint2* __restrict__ H2, const int* __restrict__ rowbeg,
    const unsigned short* __restrict__ deg, const unsigned short* __restrict__ colidx,
    const float* __restrict__ dinv, const float* __restrict__ bias,
    const unsigned short* __restrict__ WTg, unsigned short* __restrict__ HS2, int n)
{
    __shared__ unsigned short as[128 * 128];   // 32 KB: gathered h1 tile (swizzled), then result
    __shared__ unsigned short wt[128 * 128];   // 32 KB: W2^T (swizzled)
    __shared__ int nodeCur;
    const int tid = threadIdx.x;
    const int row0 = blockIdx.x * 128;

    if (tid == 0) nodeCur = 0;
    {
        const uint4* src = reinterpret_cast<const uint4*>(WTg);
        uint4* dst = reinterpret_cast<uint4*>(wt);
        int t0 = tid, t1 = tid + 1024;
        dst[(t0 & ~15) | ((t0 & 15) ^ ((t0 >> 4) & 7))] = src[t0];
        dst[(t1 & ~15) | ((t1 & 15) ^ ((t1 >> 4) & 7))] = src[t1];
    }
    __syncthreads();                           // nodeCur visible

    const int w16 = tid >> 6;
    const int lane = tid & 63;

    // ---- phase A: dynamic-cursor aggregation into (swizzled) LDS ----
    uint2* asu2 = reinterpret_cast<uint2*>(as);
    for (;;) {
        int rr = 0;
        if (lane == 0) rr = atomicAdd(&nodeCur, 1);
        rr = __shfl(rr, 0);
        if (rr >= 128) break;
        int node = row0 + rr;
        if (node < n) {
            uint2 o = agg_node(H2, rowbeg, deg, colidx, dinv, bias, node, lane);
            if ((lane >> 5) == 0) {
                int sub = lane & 31;
                asu2[rr * 32 + (sub ^ ((rr & 7) << 1))] = o;   // = ushort swz(rr, sub*4)/4
            }
        }
    }
    __syncthreads();

    // ---- phase B: as(128x128 bf16 h1-tile) @ wt -> *dinv -> HS2 ----
    const int quad = lane >> 4;
    const int col0 = lane & 15;
    const int wr  = w16 >> 1;        // rowtile 0..7
    const int nt0 = (w16 & 1) * 4;   // coltile base (0 or 4)

    s8v afr[4];
#pragma unroll
    for (int kt = 0; kt < 4; ++kt) {
        int rA = wr * 16 + col0;
        afr[kt] = *reinterpret_cast<const s8v*>(
            &as[rA * 128 + swz(rA, kt * 32 + quad * 8)]);
    }

    f4v acc[4];
#pragma unroll
    for (int nt = 0; nt < 4; ++nt) acc[nt] = (f4v){0.f, 0.f, 0.f, 0.f};

#pragma unroll
    for (int nt = 0; nt < 4; ++nt) {
        s8v bfr[4];
#pragma unroll
        for (int kt = 0; kt < 4; ++kt) {
            int rB = (nt0 + nt) * 16 + col0;
            bfr[kt] = *reinterpret_cast<const s8v*>(
                &wt[rB * 128 + swz(rB, kt * 32 + quad * 8)]);
        }
#pragma unroll
        for (int kt = 0; kt < 4; ++kt)
            acc[nt] = __builtin_amdgcn_mfma_f32_16x16x32_bf16(
                afr[kt], bfr[kt], acc[nt], 0, 0, 0);
    }

    float dv[4];
#pragma unroll
    for (int reg = 0; reg < 4; ++reg) {
        int r = row0 + wr * 16 + quad * 4 + reg;
        dv[reg] = (r < n) ? dinv[r] : 0.f;
    }
    __syncthreads();                 // all afr reads done before as overwrite
#pragma unroll
    for (int nt = 0; nt < 4; ++nt)
#pragma unroll
        for (int reg = 0; reg < 4; ++reg) {
            int rl = wr * 16 + quad * 4 + reg;
            as[rl * 128 + swz(rl, (nt0 + nt) * 16 + col0)] = f2bf(acc[nt][reg] * dv[reg]);
        }
    __syncthreads();
#pragma unroll
    for (int i = 0; i < 2; ++i) {
        int f = tid + i * 1024;
        int r = f >> 4, c8 = f & 15;
        if (row0 + r < n)
            *reinterpret_cast<uint4*>(&HS2[(size_t)(row0 + r) * 128 + c8 * 8]) =
                *reinterpret_cast<const uint4*>(&as[r * 128 + swz(r, c8 * 8)]);
    }
}

// ---------- FUSED: conv2 aggregate -> LDS rows -> segment-pool -> atomicAdd pooled ----------
// (round-2 proven version: NO MLP in here — keeping register pressure low so the
// gather loop never spills; the MLP-fusion attempt spilled 64 MB of scratch.)
__global__ __launch_bounds__(1024, 8) void agg_pool_kernel(
    const uint2* __restrict__ H2, const int* __restrict__ rowbeg,
    const unsigned short* __restrict__ deg, const unsigned short* __restrict__ colidx,
    const float* __restrict__ dinv, const float* __restrict__ bias,
    const int* __restrict__ batch, float* __restrict__ pooled, int n)
{
    __shared__ unsigned short as[128 * 128];   // 32 KB: bf16 conv2 rows
    __shared__ int bsh[128];
    __shared__ float psum[8][132];
    __shared__ int nodeCur;
    const int tid = threadIdx.x;
    const int row0 = blockIdx.x * 128;
    if (tid == 0) nodeCur = 0;
    if (tid < 128) bsh[tid] = (row0 + tid < n) ? batch[row0 + tid] : -1;
    __syncthreads();

    const int lane = tid & 63;
    uint2* asu2 = reinterpret_cast<uint2*>(as);
    for (;;) {
        int rr = 0;
        if (lane == 0) rr = atomicAdd(&nodeCur, 1);
        rr = __shfl(rr, 0);
        if (rr >= 128) break;
        int node = row0 + rr;
        if (node < n) {
            uint2 o = agg_node(H2, rowbeg, deg, colidx, dinv, bias, node, lane);
            if ((lane >> 5) == 0) asu2[rr * 32 + (lane & 31)] = o;
        }
    }
    __syncthreads();

    const int g0 = bsh[0];
    int last = row0 + 127; if (last > n - 1) last = n - 1;
    const int g1 = batch[last];
    const int s = tid >> 7;          // stripe 0..7
    const int f = tid & 127;
    for (int g = g0; g <= g1; ++g) {
        float acc = 0.f;
        for (int r = s; r < 128; r += 8)
            if (bsh[r] == g) acc += bf_us(as[r * 128 + f]);
        psum[s][f] = acc;
        __syncthreads();
        if (tid < 128) {
            float tot = 0.f;
#pragma unroll
            for (int q = 0; q < 8; ++q) tot += psum[q][f];
            atomicAdd(&pooled[g * 128 + f], tot);
        }
        __syncthreads();
    }
}

// ---------- tail: reads pooled[G][128] directly ----------
__global__ __launch_bounds__(256) void tail_kernel(
    const float* __restrict__ pooled,
    const int* __restrict__ cell, const float* __restrict__ emb,
    const float* __restrict__ Wc, const float* __restrict__ bc,
    const float* __restrict__ lncw, const float* __restrict__ lncb,
    const float* __restrict__ Wf1, const float* __restrict__ bf1,
    const float* __restrict__ ln1w, const float* __restrict__ ln1b,
    const float* __restrict__ Wf2, const float* __restrict__ bf2,
    float* __restrict__ out)
{
    __shared__ __align__(16) float comb[192];
    __shared__ __align__(16) float part[8][132];
    __shared__ float red[4];
    __shared__ __align__(16) float vec[128];
    const int gi = blockIdx.x;
    const int tid = threadIdx.x;
    const int cg = tid & 31;
    const int ks = tid >> 5;

    if (tid < 128) comb[tid] = pooled[gi * 128 + tid];
    else if (tid < 192) comb[tid] = emb[cell[gi] * 64 + (tid - 128)];
    __syncthreads();

    // ---- layer A: comb @ Wc ----
    {
        float c[24];
#pragma unroll
        for (int i = 0; i < 6; ++i) {
            float4 t = *reinterpret_cast<const float4*>(&comb[ks * 24 + i * 4]);
            c[i * 4 + 0] = t.x; c[i * 4 + 1] = t.y; c[i * 4 + 2] = t.z; c[i * 4 + 3] = t.w;
        }
        float a0 = 0.f, a1 = 0.f, a2 = 0.f, a3 = 0.f;
#pragma unroll
        for (int i = 0; i < 24; ++i) {
            const float4 w = *reinterpret_cast<const float4*>(&Wc[(ks * 24 + i) * 128 + cg * 4]);
            a0 = fmaf(c[i], w.x, a0);
            a1 = fmaf(c[i], w.y, a1);
            a2 = fmaf(c[i], w.z, a2);
            a3 = fmaf(c[i], w.w, a3);
        }
        float4 o; o.x = a0; o.y = a1; o.z = a2; o.w = a3;
        *reinterpret_cast<float4*>(&part[ks][cg * 4]) = o;
    }
    __syncthreads();
    {
        float y = 0.f;
        if (tid < 128) {
            y = bc[tid];
#pragma unroll
            for (int s = 0; s < 8; ++s) y += part[s][tid];
        }
        float s1 = (tid < 128) ? y : 0.f;
        float s2 = (tid < 128) ? y * y : 0.f;
        if (tid < 128) {
#pragma unroll
            for (int off = 32; off > 0; off >>= 1) {
                s1 += __shfl_down(s1, off);
                s2 += __shfl_down(s2, off);
            }
            if ((tid & 63) == 0) { red[(tid >> 6) * 2] = s1; red[(tid >> 6) * 2 + 1] = s2; }
        }
        __syncthreads();
        float mu = (red[0] + red[2]) * (1.f / 128.f);
        float ms = (red[1] + red[3]) * (1.f / 128.f);
        float var = ms - mu * mu;
        if (tid < 128) {
            float yv = (y - mu) * rsqrtf(var + EPS) * lncw[tid] + lncb[tid];
            vec[tid] = fmaxf(yv, 0.f);
        }
    }
    __syncthreads();

    // ---- layer B: vec @ Wf1, relu, LN ----
    {
        float c[16];
#pragma unroll
        for (int i = 0; i < 4; ++i) {
            float4 t = *reinterpret_cast<const float4*>(&vec[ks * 16 + i * 4]);
            c[i * 4 + 0] = t.x; c[i * 4 + 1] = t.y; c[i * 4 + 2] = t.z; c[i * 4 + 3] = t.w;
        }
        float a0 = 0.f, a1 = 0.f, a2 = 0.f, a3 = 0.f;
#pragma unroll
        for (int i = 0; i < 16; ++i) {
            const float4 w = *reinterpret_cast<const float4*>(&Wf1[(ks * 16 + i) * 128 + cg * 4]);
            a0 = fmaf(c[i], w.x, a0);
            a1 = fmaf(c[i], w.y, a1);
            a2 = fmaf(c[i], w.z, a2);
            a3 = fmaf(c[i], w.w, a3);
        }
        float4 o; o.x = a0; o.y = a1; o.z = a2; o.w = a3;
        *reinterpret_cast<float4*>(&part[ks][cg * 4]) = o;
    }
    __syncthreads();
    {
        float y = 0.f;
        if (tid < 128) {
            y = bf1[tid];
#pragma unroll
            for (int s = 0; s < 8; ++s) y += part[s][tid];
            y = fmaxf(y, 0.f);                 // relu BEFORE LN
        }
        float s1 = (tid < 128) ? y : 0.f;
        float s2 = (tid < 128) ? y * y : 0.f;
        if (tid < 128) {
#pragma unroll
            for (int off = 32; off > 0; off >>= 1) {
                s1 += __shfl_down(s1, off);
                s2 += __shfl_down(s2, off);
            }
            if ((tid & 63) == 0) { red[(tid >> 6) * 2] = s1; red[(tid >> 6) * 2 + 1] = s2; }
        }
        __syncthreads();
        float mu = (red[0] + red[2]) * (1.f / 128.f);
        float ms = (red[1] + red[3]) * (1.f / 128.f);
        float var = ms - mu * mu;
        if (tid < 128)
            vec[tid] = (y - mu) * rsqrtf(var + EPS) * ln1w[tid] + ln1b[tid];   // no relu
    }
    __syncthreads();

    // ---- layer C: vec @ Wf2 ----
    {
        float c[16];
#pragma unroll
        for (int i = 0; i < 4; ++i) {
            float4 t = *reinterpret_cast<const float4*>(&vec[ks * 16 + i * 4]);
            c[i * 4 + 0] = t.x; c[i * 4 + 1] = t.y; c[i * 4 + 2] = t.z; c[i * 4 + 3] = t.w;
        }
        float a0 = 0.f, a1 = 0.f, a2 = 0.f, a3 = 0.f;
#pragma unroll
        for (int i = 0; i < 16; ++i) {
            const float4 w = *reinterpret_cast<const float4*>(&Wf2[(ks * 16 + i) * 128 + cg * 4]);
            a0 = fmaf(c[i], w.x, a0);
            a1 = fmaf(c[i], w.y, a1);
            a2 = fmaf(c[i], w.z, a2);
            a3 = fmaf(c[i], w.w, a3);
        }
        float4 o; o.x = a0; o.y = a1; o.z = a2; o.w = a3;
        *reinterpret_cast<float4*>(&part[ks][cg * 4]) = o;
    }
    __syncthreads();
    if (tid < 128) {
        float y = bf2[tid];
#pragma unroll
        for (int s = 0; s < 8; ++s) y += part[s][tid];
        out[gi * 128 + tid] = y;
    }
}

// ---------- host launch ----------
extern "C" void kernel_launch(void* const* d_in, const int* in_sizes, int n_in,
                              void* d_out, int out_size, void* d_ws, size_t ws_size,
                              hipStream_t stream) {
    const float* x    = (const float*)d_in[0];
    const int*   ei   = (const int*)d_in[1];
    const int*   batch= (const int*)d_in[2];
    const int*   cell = (const int*)d_in[3];
    const float* W1   = (const float*)d_in[4];
    const float* b1   = (const float*)d_in[5];
    const float* W2   = (const float*)d_in[6];
    const float* b2   = (const float*)d_in[7];
    const float* emb  = (const float*)d_in[8];
    const float* Wc   = (const float*)d_in[9];
    const float* bc   = (const float*)d_in[10];
    const float* lncw = (const float*)d_in[11];
    const float* lncb = (const float*)d_in[12];
    const float* Wf1  = (const float*)d_in[13];
    const float* bf1  = (const float*)d_in[14];
    const float* ln1w = (const float*)d_in[15];
    const float* ln1b = (const float*)d_in[16];
    const float* Wf2  = (const float*)d_in[17];
    const float* bf2  = (const float*)d_in[18];
    float* out = (float*)d_out;

    char* ws = (char*)d_ws;
    size_t off = 0;
    auto alloc = [&](size_t bytes) { char* p = ws + off; off = (off + bytes + 255) & ~size_t(255); return p; };
    // bucketCursor + pooled adjacent -> single memset clears both
    int*            bucketCursor= (int*)  alloc(1024);                    // 196*4 used
    float*          pooled      = (float*)alloc((size_t)NGRAPH * 128 * 4);// 256 KB
    float*          dinv        = (float*)alloc(N_NODES * 4);
    int*            rowbeg      = (int*)  alloc(N_NODES * 4);
    unsigned short* deg         = (unsigned short*)alloc(N_NODES * 2);
    unsigned short* colidx      = (unsigned short*)alloc((size_t)NBUCK * BCAP * 2);
    unsigned int*   recbuf      = (unsigned int*)alloc((size_t)NBUCK * BCAP * 4);
    unsigned short* wt1         = (unsigned short*)alloc(128 * 128 * 2);
    unsigned short* wt2         = (unsigned short*)alloc(128 * 128 * 2);
    unsigned short* hs          = (unsigned short*)alloc((size_t)N_NODES * 128 * 2);
    unsigned short* hs2         = (unsigned short*)alloc((size_t)N_NODES * 128 * 2);

    const int nbEdge = (NEDGE + EPB - 1) / EPB;        // 196
    const int nbGemm = (N_NODES + 127) / 128;          // 391

    // zero cursor + pooled (stream-ordered memset node; capture-safe)
    hipMemsetAsync(bucketCursor, 0, 1024 + (size_t)NGRAPH * 128 * 4, stream);

    // scatter + weight cast (merged)
    scatter_wcast_kernel<<<nbEdge + 128, 256, 0, stream>>>(ei, bucketCursor, recbuf, NEDGE,
                                                           W1, W2, wt1, wt2);
    bucket_csr_kernel<<<NBUCK, 256, 0, stream>>>(recbuf, bucketCursor, rowbeg, deg, dinv, colidx);

    // conv1 GEMM: hs = (X @ W1) * dinv
    gemm_mfma_kernel<true><<<nbGemm, 256, 0, stream>>>(x, wt1, dinv, hs, N_NODES);

    // FUSED: agg(conv1 epilogue: +b1, relu) -> LDS tile -> @W2 -> *dinv -> hs2
    fused_agg_gemm_kernel<<<nbGemm, 1024, 0, stream>>>(
        (const uint2*)hs, rowbeg, deg, colidx, dinv, b1, wt2, hs2, N_NODES);

    // FUSED: conv2 aggregate + segment pooling -> pooled[G][128]
    agg_pool_kernel<<<nbGemm, 1024, 0, stream>>>(
        (const uint2*)hs2, rowbeg, deg, colidx, dinv, b2, batch, pooled, N_NODES);

    // tail MLP
    tail_kernel<<<NGRAPH, 256, 0, stream>>>(pooled, cell, emb, Wc, bc, lncw, lncb,
                                            Wf1, bf1, ln1w, ln1b, Wf2, bf2, out);
}